// Round 1
// baseline (112.662 us; speedup 1.0000x reference)
//
#include <hip/hip_runtime.h>

// NNLoss: bidirectional Chamfer-style nearest-neighbor L1 loss.
// B=16 batches, N=M=2048 points, D=2. Output: scalar f32 sum.
//
// Strategy: fused brute-force NN. One block = (dir, batch, 256-query tile).
// db points for the batch staged in LDS (16 KB). Each thread owns one query
// point, scans all 2048 db points (LDS broadcast reads), tracks argmin via
// 4 independent compare chains (ILP — only 1 wave/SIMD resident, so the
// serial select chain must be split). Merge with strict '<' so the lowest
// chain (lowest indices) wins ties == jnp.argmin first-index semantics.

constexpr int B     = 16;
constexpr int NPTS  = 2048;
constexpr int BLK   = 256;
constexpr int TILES = NPTS / BLK;   // 8 query tiles per (dir, batch)
constexpr int CHAINS = 4;
constexpr int QLEN   = NPTS / CHAINS; // 512

__global__ __launch_bounds__(BLK) void nnloss_kernel(
    const float* __restrict__ preds,
    const float* __restrict__ targs,
    const float* __restrict__ subcoef,
    float* __restrict__ out)
{
    __shared__ float2 sdb[NPTS];
    __shared__ float  ssum[BLK / 64];

    const int bid  = blockIdx.x;
    const int dir  = bid >> 7;           // 0: preds->targs (subcoef), 1: targs->preds
    const int rem  = bid & 127;
    const int b    = rem >> 3;
    const int tile = rem & 7;

    const float* qbase = (dir == 0) ? preds : targs;
    const float* dbase = (dir == 0) ? targs : preds;
    const float2* q  = reinterpret_cast<const float2*>(qbase) + b * NPTS;
    const float2* db = reinterpret_cast<const float2*>(dbase) + b * NPTS;

    // Stage this batch's db points into LDS (coalesced float2 loads).
    for (int i = threadIdx.x; i < NPTS; i += BLK) sdb[i] = db[i];
    __syncthreads();

    const int n = tile * BLK + threadIdx.x;
    const float2 qp = q[n];

    // 4 independent argmin chains over contiguous quarters of the db.
    float best[CHAINS];
    int   bidx[CHAINS];
    #pragma unroll
    for (int c = 0; c < CHAINS; ++c) { best[c] = 3.402823466e+38f; bidx[c] = 0; }

    for (int m = 0; m < QLEN; ++m) {
        #pragma unroll
        for (int c = 0; c < CHAINS; ++c) {
            const int idx = c * QLEN + m;
            const float2 t = sdb[idx];          // wave-uniform LDS broadcast
            const float dx = qp.x - t.x;
            const float dy = qp.y - t.y;
            const float d2 = fmaf(dx, dx, dy * dy);
            if (d2 < best[c]) { best[c] = d2; bidx[c] = idx; }  // strict < keeps first index
        }
    }

    // Merge chains: strict < means lower chain (smaller indices) wins ties.
    float bd = best[0]; int bi = bidx[0];
    #pragma unroll
    for (int c = 1; c < CHAINS; ++c) {
        if (best[c] < bd) { bd = best[c]; bi = bidx[c]; }
    }

    const float2 t = sdb[bi];
    float sx = 1.0f, sy = 1.0f;
    if (dir == 0) { sx = subcoef[0]; sy = subcoef[1]; }
    float val = fabsf(qp.x - t.x) * sx + fabsf(qp.y - t.y) * sy;

    // Wave64 shuffle reduction, then cross-wave via LDS, one atomic per block.
    #pragma unroll
    for (int off = 32; off > 0; off >>= 1)
        val += __shfl_down(val, off, 64);
    if ((threadIdx.x & 63) == 0) ssum[threadIdx.x >> 6] = val;
    __syncthreads();
    if (threadIdx.x == 0) {
        float s = ssum[0];
        #pragma unroll
        for (int w = 1; w < BLK / 64; ++w) s += ssum[w];
        atomicAdd(out, s);
    }
}

extern "C" void kernel_launch(void* const* d_in, const int* in_sizes, int n_in,
                              void* d_out, int out_size, void* d_ws, size_t ws_size,
                              hipStream_t stream) {
    const float* preds   = (const float*)d_in[0];
    const float* targs   = (const float*)d_in[1];
    const float* subcoef = (const float*)d_in[2];
    float* out = (float*)d_out;

    // Harness poisons d_out with 0xAA before every launch — zero it first.
    hipMemsetAsync(out, 0, sizeof(float), stream);

    const int grid = 2 * B * TILES;   // 2 directions * 16 batches * 8 tiles = 256
    nnloss_kernel<<<grid, BLK, 0, stream>>>(preds, targs, subcoef, out);
}

// Round 2
// 83.481 us; speedup vs baseline: 1.3495x; 1.3495x over previous
//
#include <hip/hip_runtime.h>

// NNLoss: bidirectional Chamfer NN-L1. B=16, N=M=2048, D=2, scalar f32 out.
//
// R1: occupancy was 1 wave/SIMD (latency-bound, VALUBusy 42%). Fix: split the
// db scan into S segments -> 64*S blocks (S=16 => 4 waves/SIMD). Kernel 1
// writes per-(segment,query) packed argmin candidates (monotone-float-bits<<32
// | idx) to ws; kernel 2 u64-min-merges (exact first-index tie-break), forms
// L1, reduces. Q=4 queries/thread so one uniform ds_read_b128 (2 points)
// serves 8 pairs; t^2-2q.t form cuts VALU to ~5.5 ops/pair.

constexpr int B    = 16;
constexpr int NPTS = 2048;
constexpr int BLK  = 256;
constexpr int QPT  = 4;               // queries per thread
constexpr int QPB  = BLK * QPT;       // 1024 queries per block
constexpr int NGRP = 2 * B * (NPTS / QPB);  // 64 (dir, batch, half) groups
constexpr int NQ   = 2 * B * NPTS;    // 65536 total queries

__global__ __launch_bounds__(BLK) void nn_partial(
    const float* __restrict__ preds, const float* __restrict__ targs,
    unsigned long long* __restrict__ ws, int S)
{
    extern __shared__ float4 sdb4[];   // segLen/2 float4 (= point pairs)
    const int segLen = NPTS / S;

    const int blk  = blockIdx.x;
    const int seg  = blk % S;
    const int g    = blk / S;
    const int dir  = g >> 5;
    const int b    = (g >> 1) & 15;
    const int half = g & 1;

    const float2* qb = reinterpret_cast<const float2*>(dir == 0 ? preds : targs)
                       + b * NPTS + half * QPB;
    const float2* db = reinterpret_cast<const float2*>(dir == 0 ? targs : preds)
                       + b * NPTS + seg * segLen;

    // Stage this segment into LDS (coalesced float2).
    float2* sdb2 = reinterpret_cast<float2*>(sdb4);
    for (int i = threadIdx.x; i < segLen; i += BLK) sdb2[i] = db[i];
    __syncthreads();

    // Q=4 register-resident queries (stride-BLK -> coalesced loads).
    float m2x[QPT], m2y[QPT], best[QPT];
    int   bi[QPT];
    #pragma unroll
    for (int q = 0; q < QPT; ++q) {
        const float2 qp = qb[threadIdx.x + q * BLK];
        m2x[q] = -2.0f * qp.x;
        m2y[q] = -2.0f * qp.y;
        best[q] = 3.402823466e+38f;
        bi[q] = 0;
    }

    // Scan segment: f(t) = t^2 - 2 q.t  (monotone in d^2 per query).
    // One uniform ds_read_b128 per iter = 2 db points for 4 queries = 8 pairs.
    const int idxBase = seg * segLen;
    const int iters = segLen >> 1;
    #pragma unroll 8
    for (int i = 0; i < iters; ++i) {
        const float4 p = sdb4[i];
        const float t20 = fmaf(p.x, p.x, p.y * p.y);
        const float t21 = fmaf(p.z, p.z, p.w * p.w);
        const int i0 = idxBase + 2 * i;
        #pragma unroll
        for (int q = 0; q < QPT; ++q) {
            const float d0 = fmaf(m2x[q], p.x, fmaf(m2y[q], p.y, t20));
            if (d0 < best[q]) { best[q] = d0; bi[q] = i0; }       // strict <:
            const float d1 = fmaf(m2x[q], p.z, fmaf(m2y[q], p.w, t21));
            if (d1 < best[q]) { best[q] = d1; bi[q] = i0 + 1; }   // first idx wins
        }
    }

    // Pack: monotone-ordered float bits in high 32, global idx in low 32.
    const int qid0 = (dir * B + b) * NPTS + half * QPB + threadIdx.x;
    unsigned long long* wseg = ws + (size_t)seg * NQ;
    #pragma unroll
    for (int q = 0; q < QPT; ++q) {
        unsigned int fb = __float_as_uint(best[q]);
        fb ^= 0x80000000u | (unsigned int)((int)fb >> 31);  // total-order map
        wseg[qid0 + q * BLK] =
            ((unsigned long long)fb << 32) | (unsigned int)bi[q];
    }
}

__global__ __launch_bounds__(BLK) void nn_finish(
    const float* __restrict__ preds, const float* __restrict__ targs,
    const float* __restrict__ subcoef,
    const unsigned long long* __restrict__ ws, int S,
    float* __restrict__ out)
{
    __shared__ float ssum[BLK / 64];
    const int qid = blockIdx.x * BLK + threadIdx.x;

    unsigned long long bestp = ~0ULL;
    for (int s = 0; s < S; ++s) {
        const unsigned long long v = ws[(size_t)s * NQ + qid];
        bestp = v < bestp ? v : bestp;   // min packed == min f, then min idx
    }
    const int idx = (int)(unsigned int)bestp;

    const int dir = qid >> 15;
    const int rem = qid & 32767;
    const int b   = rem >> 11;
    const int n   = rem & 2047;
    const float2* qb = reinterpret_cast<const float2*>(dir == 0 ? preds : targs)
                       + b * NPTS;
    const float2* db = reinterpret_cast<const float2*>(dir == 0 ? targs : preds)
                       + b * NPTS;
    const float2 qp = qb[n];
    const float2 tp = db[idx];

    float sx = 1.0f, sy = 1.0f;
    if (dir == 0) { sx = subcoef[0]; sy = subcoef[1]; }
    float val = fabsf(qp.x - tp.x) * sx + fabsf(qp.y - tp.y) * sy;

    #pragma unroll
    for (int off = 32; off > 0; off >>= 1)
        val += __shfl_down(val, off, 64);
    if ((threadIdx.x & 63) == 0) ssum[threadIdx.x >> 6] = val;
    __syncthreads();
    if (threadIdx.x == 0) {
        float s = ssum[0];
        #pragma unroll
        for (int w = 1; w < BLK / 64; ++w) s += ssum[w];
        atomicAdd(out, s);
    }
}

extern "C" void kernel_launch(void* const* d_in, const int* in_sizes, int n_in,
                              void* d_out, int out_size, void* d_ws, size_t ws_size,
                              hipStream_t stream) {
    const float* preds   = (const float*)d_in[0];
    const float* targs   = (const float*)d_in[1];
    const float* subcoef = (const float*)d_in[2];
    float* out = (float*)d_out;
    unsigned long long* ws = (unsigned long long*)d_ws;

    // Segments chosen from available scratch (deterministic across calls).
    const size_t per_seg = (size_t)NQ * sizeof(unsigned long long);  // 512 KB
    int S = 1;
    if      (ws_size >= 16 * per_seg) S = 16;
    else if (ws_size >=  8 * per_seg) S = 8;
    else if (ws_size >=  4 * per_seg) S = 4;
    else if (ws_size >=  2 * per_seg) S = 2;

    hipMemsetAsync(out, 0, sizeof(float), stream);

    const int segLen = NPTS / S;
    nn_partial<<<NGRP * S, BLK, segLen * sizeof(float2), stream>>>(
        preds, targs, ws, S);
    nn_finish<<<NQ / BLK, BLK, 0, stream>>>(preds, targs, subcoef, ws, S, out);
}

// Round 3
// 76.061 us; speedup vs baseline: 1.4812x; 1.0976x over previous
//
#include <hip/hip_runtime.h>

// NNLoss: bidirectional Chamfer NN-L1. B=16, N=M=2048, D=2, scalar f32 out.
//
// R2: fuse segment-split NN + merge into ONE kernel. 256 blocks x 1024 thr
// (1 block/CU, 16 waves = 4 waves/SIMD). Block owns (dir,b,256-query tile);
// db split S=16 ways across waves (thread = 4 queries x 1 segment; inner loop
// identical to R1's proven one). Packed (monotone_fb<<32|idx) candidates meet
// in LDS; u64-min merge keeps exact jnp.argmin first-index semantics. Block
// writes one partial sum to ws; tiny 1-block kernel finishes. No memset, no
// 8 MB ws round-trip, 2 dispatches total.

constexpr int B      = 16;
constexpr int NPTS   = 2048;
constexpr int BLK    = 1024;
constexpr int G      = 256;          // queries per block
constexpr int S      = 16;           // db segments (one per wave)
constexpr int QPT    = 4;            // queries per thread
constexpr int SEGLEN = NPTS / S;     // 128 points per segment
constexpr int ITERS  = SEGLEN / 2;   // 64 float4 iters
constexpr int NBLK   = 2 * B * (NPTS / G);  // 256 blocks

__global__ __launch_bounds__(BLK) void nn_main(
    const float* __restrict__ preds, const float* __restrict__ targs,
    const float* __restrict__ subcoef, float* __restrict__ ws_out)
{
    __shared__ float4 sdb4[NPTS / 2];                  // 16 KB db stage
    __shared__ unsigned long long cand[S][G];          // 32 KB candidates
    __shared__ float ssum[BLK / 64];

    const int blk  = blockIdx.x;
    const int dir  = blk >> 7;          // 0: preds->targs (subcoef), 1: reverse
    const int b    = (blk >> 3) & 15;
    const int tile = blk & 7;

    const float2* qb = reinterpret_cast<const float2*>(dir == 0 ? preds : targs)
                       + b * NPTS + tile * G;
    const float2* db = reinterpret_cast<const float2*>(dir == 0 ? targs : preds)
                       + b * NPTS;

    // Stage full db batch (coalesced float4, exactly 1 per thread).
    const float4* db4 = reinterpret_cast<const float4*>(db);
    for (int i = threadIdx.x; i < NPTS / 2; i += BLK) sdb4[i] = db4[i];

    const int qslot = threadIdx.x & 63;   // query slot within wave
    const int seg   = threadIdx.x >> 6;   // one segment per wave

    // 4 register-resident queries (coalesced: lanes read consecutive float2).
    float m2x[QPT], m2y[QPT], best[QPT];
    int   bi[QPT];
    #pragma unroll
    for (int q = 0; q < QPT; ++q) {
        const float2 qp = qb[qslot + q * 64];
        m2x[q] = -2.0f * qp.x;
        m2y[q] = -2.0f * qp.y;
        best[q] = 3.402823466e+38f;
        bi[q] = 0;
    }
    __syncthreads();

    // Scan segment: f(t) = t^2 - 2 q.t (monotone in d^2 per query).
    // Wave-uniform ds_read_b128 = 2 points for 4 queries = 8 pairs/iter.
    const int pbase   = seg * ITERS;
    const int idxBase = seg * SEGLEN;
    #pragma unroll 8
    for (int i = 0; i < ITERS; ++i) {
        const float4 p = sdb4[pbase + i];
        const float t20 = fmaf(p.x, p.x, p.y * p.y);
        const float t21 = fmaf(p.z, p.z, p.w * p.w);
        const int i0 = idxBase + 2 * i;
        #pragma unroll
        for (int q = 0; q < QPT; ++q) {
            const float d0 = fmaf(m2x[q], p.x, fmaf(m2y[q], p.y, t20));
            if (d0 < best[q]) { best[q] = d0; bi[q] = i0; }       // strict <:
            const float d1 = fmaf(m2x[q], p.z, fmaf(m2y[q], p.w, t21));
            if (d1 < best[q]) { best[q] = d1; bi[q] = i0 + 1; }   // first idx wins
        }
    }

    // Publish packed candidates: monotone-ordered f bits high, global idx low.
    #pragma unroll
    for (int q = 0; q < QPT; ++q) {
        unsigned int fb = __float_as_uint(best[q]);
        fb ^= 0x80000000u | (unsigned int)((int)fb >> 31);  // total-order map
        cand[seg][qslot + q * 64] =
            ((unsigned long long)fb << 32) | (unsigned int)bi[q];
    }
    __syncthreads();

    // First 256 threads: merge 16 segment candidates (u64 min = exact argmin).
    float val = 0.0f;
    if (threadIdx.x < G) {
        unsigned long long bp = cand[0][threadIdx.x];
        #pragma unroll
        for (int s = 1; s < S; ++s) {
            const unsigned long long v = cand[s][threadIdx.x];
            bp = v < bp ? v : bp;
        }
        const int idx = (int)(unsigned int)bp;
        const float2 qp = qb[threadIdx.x];
        const float2 tp = db[idx];
        float sx = 1.0f, sy = 1.0f;
        if (dir == 0) { sx = subcoef[0]; sy = subcoef[1]; }
        val = fabsf(qp.x - tp.x) * sx + fabsf(qp.y - tp.y) * sy;
    }

    // Block reduction (all 1024 threads; inactive hold 0).
    #pragma unroll
    for (int off = 32; off > 0; off >>= 1)
        val += __shfl_down(val, off, 64);
    if ((threadIdx.x & 63) == 0) ssum[threadIdx.x >> 6] = val;
    __syncthreads();
    if (threadIdx.x == 0) {
        float s = ssum[0];
        #pragma unroll
        for (int w = 1; w < BLK / 64; ++w) s += ssum[w];
        ws_out[blk] = s;   // deterministic write, no atomics, no init needed
    }
}

__global__ __launch_bounds__(NBLK) void nn_reduce(
    const float* __restrict__ ws_in, float* __restrict__ out)
{
    __shared__ float ssum[NBLK / 64];
    float val = ws_in[threadIdx.x];
    #pragma unroll
    for (int off = 32; off > 0; off >>= 1)
        val += __shfl_down(val, off, 64);
    if ((threadIdx.x & 63) == 0) ssum[threadIdx.x >> 6] = val;
    __syncthreads();
    if (threadIdx.x == 0) {
        float s = ssum[0];
        #pragma unroll
        for (int w = 1; w < NBLK / 64; ++w) s += ssum[w];
        out[0] = s;
    }
}

extern "C" void kernel_launch(void* const* d_in, const int* in_sizes, int n_in,
                              void* d_out, int out_size, void* d_ws, size_t ws_size,
                              hipStream_t stream) {
    const float* preds   = (const float*)d_in[0];
    const float* targs   = (const float*)d_in[1];
    const float* subcoef = (const float*)d_in[2];
    float* out = (float*)d_out;
    float* ws  = (float*)d_ws;

    nn_main<<<NBLK, BLK, 0, stream>>>(preds, targs, subcoef, ws);
    nn_reduce<<<1, NBLK, 0, stream>>>(ws, out);
}